// Round 18
// baseline (129.045 us; speedup 1.0000x reference)
//
#include <hip/hip_runtime.h>
#include <hip/hip_bf16.h>
#include <cstdint>
#include <cstddef>

typedef __attribute__((ext_vector_type(8))) short bf16x8;
typedef __attribute__((ext_vector_type(4))) float f32x4;
typedef __attribute__((ext_vector_type(4))) unsigned int u32x4;

#define T_DIM 2048
#define C_DIM 1024
#define B_DIM 8
#define NEG_BIG (-3.0e38f)
#define QSCALE 0.18033688011112042f   // (1/8) * log2(e): softmax in exp2 domain

__device__ __forceinline__ unsigned short f2bf(float f) {
  union { __hip_bfloat16 h; unsigned short u; } cv;
  cv.h = __float2bfloat16(f);
  return cv.u;
}
__device__ __forceinline__ f32x4 mfma16(bf16x8 a, bf16x8 b, f32x4 c) {
  return __builtin_amdgcn_mfma_f32_16x16x32_bf16(a, b, c, 0, 0, 0);
}

// ---------------------------------------------------------------------------
// prep_w: unchanged.
// ---------------------------------------------------------------------------
__global__ __launch_bounds__(256) void prep_w(
    const float* __restrict__ Wq, const float* __restrict__ Wk,
    const float* __restrict__ Wv, unsigned short* __restrict__ Wt)
{
  const int mtx = blockIdx.x >> 4;
  const int k0  = (blockIdx.x & 15) * 64;
  const float* W = (mtx == 0) ? Wq : ((mtx == 1) ? Wk : Wv);
  const float scale = (mtx == 0) ? QSCALE : 1.0f;
  __shared__ float Ws[64][65];
  const int t = threadIdx.x;
#pragma unroll
  for (int j = 0; j < 4; ++j) {
    int r = (t >> 4) + 16 * j;
    int c = (t & 15) * 4;
    union { float4 f4; float f[4]; } uv;
    uv.f4 = *(const float4*)&W[(size_t)(k0 + r) * 64 + c];
#pragma unroll
    for (int jj = 0; jj < 4; ++jj) Ws[c + jj][r] = uv.f[jj] * scale;
  }
  __syncthreads();
#pragma unroll
  for (int q = 0; q < 2; ++q) {
    int g_ = t + 256 * q;
    int d  = g_ >> 3;
    int ko = (g_ & 7) * 8;
    union { unsigned short u[8]; u32x4 v; } pk;
#pragma unroll
    for (int jj = 0; jj < 8; ++jj) pk.u[jj] = f2bf(Ws[d][ko + jj]);
    *(u32x4*)&Wt[((size_t)mtx * 64 + d) * C_DIM + k0 + ko] = pk.v;
  }
}

// ---------------------------------------------------------------------------
// qkv_proj_mfma: r12 pipeline + DIAGNOSTIC nrep loop (runtime bound; only
// the last rep stores to global -> no DCE of earlier reps).
// ---------------------------------------------------------------------------
__global__ __launch_bounds__(256) void qkv_proj_mfma(
    const float* __restrict__ x,
    const unsigned short* __restrict__ Wt,
    const float* __restrict__ bq, const float* __restrict__ bk, const float* __restrict__ bv,
    unsigned short* __restrict__ Qb, unsigned short* __restrict__ Kb,
    unsigned short* __restrict__ VTb, int nrep)
{
  __shared__ __align__(16) short Xs[2][32 * 64];
  __shared__ __align__(16) short Wsb[2][3 * 64 * 64];
  __shared__ __align__(16) unsigned short VTs[64 * 40];

  const int tid = threadIdx.x;
  const int wv = tid >> 6, lane = tid & 63, g = lane >> 4, ln15 = lane & 15;
  const size_t m0 = (size_t)blockIdx.x * 32;

  float4 xA[2], xB[2];
  u32x4 wr[6];

  auto issueX = [&](float4 (&xr)[2], int kt) {
    if (kt >= 16) return;
#pragma unroll
    for (int q = 0; q < 2; ++q) {
      int g_ = tid + 256 * q;
      int r = g_ >> 4, c4 = (g_ & 15) * 4;
      xr[q] = *(const float4*)&x[(m0 + r) * C_DIM + kt * 64 + c4];
    }
  };
  auto issueW = [&](int kt) {
    if (kt >= 16) return;
#pragma unroll
    for (int mt = 0; mt < 3; ++mt)
#pragma unroll
      for (int q = 0; q < 2; ++q) {
        int g_ = tid + 256 * q;
        int d = g_ >> 3, ko = (g_ & 7) * 8;
        wr[mt * 2 + q] = *(const u32x4*)&Wt[((size_t)mt * 64 + d) * C_DIM + kt * 64 + ko];
      }
  };
  auto writeXb = [&](int nb, const float4 (&xr)[2]) {
#pragma unroll
    for (int q = 0; q < 2; ++q) {
      int g_ = tid + 256 * q;
      int r = g_ >> 4, c4 = (g_ & 15) * 4;
      const float* f = (const float*)&xr[q];
      union { unsigned short u[4]; unsigned long long ll; } pk;
#pragma unroll
      for (int jj = 0; jj < 4; ++jj) pk.u[jj] = f2bf(f[jj]);
      *(unsigned long long*)((char*)Xs[nb] + r * 128 + ((c4 * 2) ^ ((r & 7) << 4))) = pk.ll;
    }
  };
  auto writeWb = [&](int nb) {
#pragma unroll
    for (int mt = 0; mt < 3; ++mt)
#pragma unroll
      for (int q = 0; q < 2; ++q) {
        int g_ = tid + 256 * q;
        int d = g_ >> 3, ko = (g_ & 7) * 8;
        *(u32x4*)((char*)Wsb[nb] + mt * 8192 + d * 128 + ((ko * 2) ^ ((d & 7) << 4))) = wr[mt * 2 + q];
      }
  };

  for (int rep = 0; rep < nrep; ++rep) {
    f32x4 acc[2][3];
#pragma unroll
    for (int mt = 0; mt < 2; ++mt)
#pragma unroll
      for (int j = 0; j < 3; ++j) acc[mt][j] = (f32x4){0.f, 0.f, 0.f, 0.f};

    auto compute = [&](int nb) {
#pragma unroll
      for (int kc = 0; kc < 2; ++kc) {
        bf16x8 a[2];
#pragma unroll
        for (int mt = 0; mt < 2; ++mt) {
          int xr = mt * 16 + ln15;
          a[mt] = *(const bf16x8*)((const char*)Xs[nb] + xr * 128 + ((kc * 64 + g * 16) ^ ((xr & 7) << 4)));
        }
#pragma unroll
        for (int j = 0; j < 3; ++j) {
          int ntg = wv * 3 + j;
          int mtx = ntg >> 2, nc = (ntg & 3) * 16;
          int wrow = nc + ln15;
          bf16x8 bb = *(const bf16x8*)((const char*)Wsb[nb] + mtx * 8192 + wrow * 128 + ((kc * 64 + g * 16) ^ ((wrow & 7) << 4)));
#pragma unroll
          for (int mt = 0; mt < 2; ++mt)
            acc[mt][j] = mfma16(a[mt], bb, acc[mt][j]);
        }
      }
    };

    issueX(xA, 0); issueW(0);
    writeXb(0, xA); writeWb(0);
    issueX(xB, 1);
    __syncthreads();

    for (int kt = 0; kt < 16; kt += 2) {
      issueW(kt + 1);
      issueX(xA, kt + 2);
      compute(0);
      if (kt + 1 < 16) { writeXb(1, xB); writeWb(1); }
      __syncthreads();
      if (kt + 1 < 16) {
        issueW(kt + 2);
        issueX(xB, kt + 3);
        compute(1);
        if (kt + 2 < 16) { writeXb(0, xA); writeWb(0); }
        __syncthreads();
      }
    }

    if (rep == nrep - 1) {
#pragma unroll
      for (int j = 0; j < 3; ++j) {
        int ntg = wv * 3 + j;
        int mtx = ntg >> 2, nc = (ntg & 3) * 16;
        if (mtx < 2) {
          const float* bias = (mtx == 0) ? bq : bk;
          unsigned short* Out = (mtx == 0) ? Qb : Kb;
          float bvv = bias[nc + ln15] * ((mtx == 0) ? QSCALE : 1.0f);
#pragma unroll
          for (int mt = 0; mt < 2; ++mt)
#pragma unroll
            for (int i = 0; i < 4; ++i)
              Out[(m0 + mt * 16 + 4 * g + i) * 64 + nc + ln15] = f2bf(acc[mt][j][i] + bvv);
        } else {
          float bvv = bv[nc + ln15];
#pragma unroll
          for (int mt = 0; mt < 2; ++mt)
#pragma unroll
            for (int i = 0; i < 4; ++i)
              VTs[(nc + ln15) * 40 + mt * 16 + 4 * g + i] = f2bf(acc[mt][j][i] + bvv);
        }
      }
      __syncthreads();
      {
        int d = tid >> 2, t8 = (tid & 3) * 8;
        u32x4 v0 = *(const u32x4*)&VTs[d * 40 + t8];
        size_t b = m0 >> 11, tloc = m0 & 2047;
        *(u32x4*)&VTb[(b * 64 + d) * T_DIM + tloc + t8] = v0;
      }
    }
  }
}

// ---------------------------------------------------------------------------
// attn_flash: r15 version + DIAGNOSTIC nrep loop (runtime bound; only the
// last rep stores to out).
// ---------------------------------------------------------------------------
__global__ __launch_bounds__(256, 2) void attn_flash(
    const unsigned short* __restrict__ Qb,
    const unsigned short* __restrict__ Kb,
    const unsigned short* __restrict__ VTb,
    float* __restrict__ out, int nrep)
{
  __shared__ __align__(16) short Ps[4][2 * 16 * 64];
  __shared__ __align__(16) float Zs[3][2][16 * 68];
  __shared__ float Ml[3][2][16][2];

  const int tid  = threadIdx.x;
  const int wv   = tid >> 6;
  const int lane = tid & 63;
  const int g    = lane >> 4;
  const int ln15 = lane & 15;

  const int qt = 63 - (blockIdx.x >> 3);
  const int b  = blockIdx.x & 7;
  const int r0 = qt * 32;
  const int ntiles = (qt >> 1) + 1;

  const size_t bT = (size_t)b * T_DIM;

  bf16x8 qa[2][2];
#pragma unroll
  for (int mt = 0; mt < 2; ++mt) {
    const unsigned short* qp = Qb + (bT + r0 + mt * 16 + ln15) * 64 + g * 8;
    qa[mt][0] = *(const bf16x8*)qp;
    qa[mt][1] = *(const bf16x8*)(qp + 32);
  }

  char* myP = (char*)Ps[wv];

  for (int rep = 0; rep < nrep; ++rep) {
    __syncthreads();   // separate reps (Zs reads of prev rep complete)

    f32x4 acc[2][4];
#pragma unroll
    for (int mt = 0; mt < 2; ++mt)
#pragma unroll
      for (int dt = 0; dt < 4; ++dt) acc[mt][dt] = (f32x4){0.f, 0.f, 0.f, 0.f};
    float m_[2], l_[2];
#pragma unroll
    for (int mt = 0; mt < 2; ++mt) { m_[mt] = NEG_BIG; l_[mt] = 0.f; }

    for (int it = wv; it < ntiles; it += 4) {
      const int s0 = it * 64;
      bf16x8 kf[4][2];
#pragma unroll
      for (int nt = 0; nt < 4; ++nt) {
        const unsigned short* kp = Kb + (bT + s0 + nt * 16 + ln15) * 64 + g * 8;
        kf[nt][0] = *(const bf16x8*)kp;
        kf[nt][1] = *(const bf16x8*)(kp + 32);
      }
      bf16x8 vf[4][2];
#pragma unroll
      for (int dt = 0; dt < 4; ++dt) {
        const unsigned short* vp = VTb + ((size_t)b * 64 + dt * 16 + ln15) * T_DIM + s0 + g * 8;
        vf[dt][0] = *(const bf16x8*)vp;
        vf[dt][1] = *(const bf16x8*)(vp + 32);
      }
      f32x4 st[2][4];
      __builtin_amdgcn_s_setprio(1);
#pragma unroll
      for (int mt = 0; mt < 2; ++mt)
#pragma unroll
        for (int nt = 0; nt < 4; ++nt) {
          f32x4 a = (f32x4){0.f, 0.f, 0.f, 0.f};
          a = mfma16(kf[nt][0], qa[mt][0], a);
          a = mfma16(kf[nt][1], qa[mt][1], a);
          st[mt][nt] = a;
        }
      __builtin_amdgcn_s_setprio(0);
      if (s0 + 63 > r0) {
#pragma unroll
        for (int mt = 0; mt < 2; ++mt) {
          const int qg = r0 + mt * 16 + ln15;
#pragma unroll
          for (int nt = 0; nt < 4; ++nt) {
            const int kvb = s0 + nt * 16 + 4 * g;
#pragma unroll
            for (int i = 0; i < 4; ++i)
              if (kvb + i > qg) st[mt][nt][i] = NEG_BIG;
          }
        }
      }
#pragma unroll
      for (int mt = 0; mt < 2; ++mt) {
        f32x4 t4;
#pragma unroll
        for (int i = 0; i < 4; ++i)
          t4[i] = fmaxf(fmaxf(st[mt][0][i], st[mt][1][i]), fmaxf(st[mt][2][i], st[mt][3][i]));
        float mx = fmaxf(fmaxf(t4[0], t4[1]), fmaxf(t4[2], t4[3]));
        if (!__all((int)(mx <= m_[mt] + 8.0f))) {
          mx = fmaxf(mx, __shfl_xor(mx, 16));
          mx = fmaxf(mx, __shfl_xor(mx, 32));
          const float mn = fmaxf(m_[mt], mx);
          const float corr = exp2f(m_[mt] - mn);
          m_[mt] = mn;
          l_[mt] *= corr;
#pragma unroll
          for (int dt = 0; dt < 4; ++dt)
#pragma unroll
            for (int i = 0; i < 4; ++i)
              acc[mt][dt][i] *= corr;
        }
#pragma unroll
        for (int nt = 0; nt < 4; ++nt)
#pragma unroll
          for (int i = 0; i < 4; ++i)
            st[mt][nt][i] = exp2f(st[mt][nt][i] - m_[mt]);
        float ps = 0.f;
#pragma unroll
        for (int nt = 0; nt < 4; ++nt)
          ps += (st[mt][nt][0] + st[mt][nt][1]) + (st[mt][nt][2] + st[mt][nt][3]);
        l_[mt] += ps;
#pragma unroll
        for (int nt = 0; nt < 4; ++nt) {
          unsigned int lo_ = (unsigned int)f2bf(st[mt][nt][0]) | ((unsigned int)f2bf(st[mt][nt][1]) << 16);
          unsigned int hi_ = (unsigned int)f2bf(st[mt][nt][2]) | ((unsigned int)f2bf(st[mt][nt][3]) << 16);
          *(unsigned long long*)(myP + mt * 2048 + ln15 * 128 +
                                 ((nt * 32 + g * 8) ^ ((ln15 & 7) << 4))) =
              ((unsigned long long)hi_ << 32) | lo_;
        }
      }
      bf16x8 pb[2][2];
#pragma unroll
      for (int mt = 0; mt < 2; ++mt)
#pragma unroll
        for (int kc = 0; kc < 2; ++kc)
          pb[mt][kc] = *(const bf16x8*)(myP + mt * 2048 + ln15 * 128 +
                                        ((kc * 64 + g * 16) ^ ((ln15 & 7) << 4)));
      __builtin_amdgcn_s_setprio(1);
#pragma unroll
      for (int mt = 0; mt < 2; ++mt)
#pragma unroll
        for (int dt = 0; dt < 4; ++dt) {
          acc[mt][dt] = mfma16(vf[dt][0], pb[mt][0], acc[mt][dt]);
          acc[mt][dt] = mfma16(vf[dt][1], pb[mt][1], acc[mt][dt]);
        }
      __builtin_amdgcn_s_setprio(0);
    }

#pragma unroll
    for (int mt = 0; mt < 2; ++mt) {
      l_[mt] += __shfl_xor(l_[mt], 16);
      l_[mt] += __shfl_xor(l_[mt], 32);
    }

    if (wv > 0) {
#pragma unroll
      for (int mt = 0; mt < 2; ++mt) {
#pragma unroll
        for (int dt = 0; dt < 4; ++dt)
          *(f32x4*)&Zs[wv - 1][mt][ln15 * 68 + dt * 16 + 4 * g] = acc[mt][dt];
        if (g == 0) {
          Ml[wv - 1][mt][ln15][0] = m_[mt];
          Ml[wv - 1][mt][ln15][1] = l_[mt];
        }
      }
    }
    __syncthreads();
    if (wv == 0) {
#pragma unroll
      for (int mt = 0; mt < 2; ++mt) {
        float mm = m_[mt];
#pragma unroll
        for (int w = 0; w < 3; ++w) mm = fmaxf(mm, Ml[w][mt][ln15][0]);
        const float e0 = exp2f(m_[mt] - mm);
        float lsum = l_[mt] * e0;
        float ew[3];
#pragma unroll
        for (int w = 0; w < 3; ++w) {
          ew[w] = exp2f(Ml[w][mt][ln15][0] - mm);
          lsum += Ml[w][mt][ln15][1] * ew[w];
        }
        const float inv = 1.0f / lsum;
        if (rep == nrep - 1) {
          float* ob = out + (bT + r0 + mt * 16 + ln15) * 64;
#pragma unroll
          for (int dt = 0; dt < 4; ++dt) {
            f32x4 z;
#pragma unroll
            for (int i = 0; i < 4; ++i) {
              float zz = acc[mt][dt][i] * e0;
#pragma unroll
              for (int w = 0; w < 3; ++w)
                zz += Zs[w][mt][ln15 * 68 + dt * 16 + 4 * g + i] * ew[w];
              z[i] = zz * inv;
            }
            *(f32x4*)&ob[dt * 16 + 4 * g] = z;
          }
        }
      }
    }
  }
}

// ---------------------------------------------------------------------------
extern "C" void kernel_launch(void* const* d_in, const int* in_sizes, int n_in,
                              void* d_out, int out_size, void* d_ws, size_t ws_size,
                              hipStream_t stream)
{
  const float* x  = (const float*)d_in[0];
  const float* Wq = (const float*)d_in[1];
  const float* bq = (const float*)d_in[2];
  const float* Wk = (const float*)d_in[3];
  const float* bk = (const float*)d_in[4];
  const float* Wv = (const float*)d_in[5];
  const float* bv = (const float*)d_in[6];
  float* out = (float*)d_out;

  char* ws = (char*)d_ws;
  unsigned short* Wt  = (unsigned short*)(ws);                      // 384 KB
  unsigned short* Qb  = (unsigned short*)(ws + (1u << 19));         // 2 MB
  unsigned short* Kb  = (unsigned short*)(ws + (1u << 19) + (1u << 21));
  unsigned short* VTb = (unsigned short*)(ws + (1u << 19) + (2u << 21));

  prep_w<<<48, 256, 0, stream>>>(Wq, Wk, Wv, Wt);
  qkv_proj_mfma<<<512, 256, 0, stream>>>(x, Wt, bq, bk, bv, Qb, Kb, VTb, 2);
  attn_flash<<<512, 256, 0, stream>>>(Qb, Kb, VTb, out, 2);
}

// Round 19
// 90.014 us; speedup vs baseline: 1.4336x; 1.4336x over previous
//
#include <hip/hip_runtime.h>
#include <hip/hip_bf16.h>
#include <cstdint>
#include <cstddef>

typedef __attribute__((ext_vector_type(8))) short bf16x8;
typedef __attribute__((ext_vector_type(4))) float f32x4;
typedef __attribute__((ext_vector_type(4))) unsigned int u32x4;

#define T_DIM 2048
#define C_DIM 1024
#define B_DIM 8
#define NEG_BIG (-3.0e38f)
#define QSCALE 0.18033688011112042f   // (1/8) * log2(e): softmax in exp2 domain

__device__ __forceinline__ unsigned short f2bf(float f) {
  union { __hip_bfloat16 h; unsigned short u; } cv;
  cv.h = __float2bfloat16(f);
  return cv.u;
}
__device__ __forceinline__ f32x4 mfma16(bf16x8 a, bf16x8 b, f32x4 c) {
  return __builtin_amdgcn_mfma_f32_16x16x32_bf16(a, b, c, 0, 0, 0);
}

// ---------------------------------------------------------------------------
// prep_w: W [1024][64] f32 -> Wt [3][64][1024] bf16 (transposed; Wq scaled by
// (1/8)*log2e so softmax runs in exp2 domain). Unchanged.
// ---------------------------------------------------------------------------
__global__ __launch_bounds__(256) void prep_w(
    const float* __restrict__ Wq, const float* __restrict__ Wk,
    const float* __restrict__ Wv, unsigned short* __restrict__ Wt)
{
  const int mtx = blockIdx.x >> 4;
  const int k0  = (blockIdx.x & 15) * 64;
  const float* W = (mtx == 0) ? Wq : ((mtx == 1) ? Wk : Wv);
  const float scale = (mtx == 0) ? QSCALE : 1.0f;
  __shared__ float Ws[64][65];
  const int t = threadIdx.x;
#pragma unroll
  for (int j = 0; j < 4; ++j) {
    int r = (t >> 4) + 16 * j;
    int c = (t & 15) * 4;
    union { float4 f4; float f[4]; } uv;
    uv.f4 = *(const float4*)&W[(size_t)(k0 + r) * 64 + c];
#pragma unroll
    for (int jj = 0; jj < 4; ++jj) Ws[c + jj][r] = uv.f[jj] * scale;
  }
  __syncthreads();
#pragma unroll
  for (int q = 0; q < 2; ++q) {
    int g_ = t + 256 * q;
    int d  = g_ >> 3;
    int ko = (g_ & 7) * 8;
    union { unsigned short u[8]; u32x4 v; } pk;
#pragma unroll
    for (int jj = 0; jj < 8; ++jj) pk.u[jj] = f2bf(Ws[d][ko + jj]);
    *(u32x4*)&Wt[((size_t)mtx * 64 + d) * C_DIM + k0 + ko] = pk.v;
  }
}

// ---------------------------------------------------------------------------
// qkv_proj_mfma: BARRIER-FREE pure-dataflow rewrite (r18 diagnostic showed
// proj latency-bound: MfmaUtil 6%, VALU 4%, HBM 9-14%; every __syncthreads
// drains vmcnt(0), defeating all prefetch). Each wave owns 16 private x-rows
// and ALL 12 n-tiles: A-frags direct global->reg (16 rows x 128B coalesced
// segments), B-frags direct from L2-resident Wt. No LDS staging, no barriers
// in the K-loop; 12 independent acc chains pipeline freely. One barrier only
// for the fused V-transpose epilogue. Grid 256 x (4 waves x 16 rows).
// ---------------------------------------------------------------------------
__global__ __launch_bounds__(256) void qkv_proj_mfma(
    const float* __restrict__ x,
    const unsigned short* __restrict__ Wt,
    const float* __restrict__ bq, const float* __restrict__ bk, const float* __restrict__ bv,
    unsigned short* __restrict__ Qb, unsigned short* __restrict__ Kb,
    unsigned short* __restrict__ VTb)
{
  __shared__ __align__(16) unsigned short VTs[64 * 72];  // V-transpose tile only

  const int tid = threadIdx.x;
  const int wv = tid >> 6, lane = tid & 63, g = lane >> 4, ln15 = lane & 15;
  const size_t m0 = (size_t)blockIdx.x * 64;
  const size_t myrow = m0 + wv * 16 + ln15;   // this lane's private x row

  f32x4 acc[12];
#pragma unroll
  for (int j = 0; j < 12; ++j) acc[j] = (f32x4){0.f, 0.f, 0.f, 0.f};

  const float* xrow = x + myrow * C_DIM + g * 8;

  auto loadA = [&](bf16x8 (&af)[2], int kt) {
    const float* p = xrow + kt * 64;
    float4 f0 = *(const float4*)(p);
    float4 f1 = *(const float4*)(p + 4);
    float4 f2 = *(const float4*)(p + 32);
    float4 f3 = *(const float4*)(p + 36);
    union { unsigned short u[8]; bf16x8 v; } p0, p1;
    const float* a0 = (const float*)&f0; const float* a1 = (const float*)&f1;
    const float* a2 = (const float*)&f2; const float* a3 = (const float*)&f3;
#pragma unroll
    for (int jj = 0; jj < 4; ++jj) {
      p0.u[jj] = f2bf(a0[jj]); p0.u[4 + jj] = f2bf(a1[jj]);
      p1.u[jj] = f2bf(a2[jj]); p1.u[4 + jj] = f2bf(a3[jj]);
    }
    af[0] = p0.v; af[1] = p1.v;
  };
  auto compW = [&](const bf16x8 (&af)[2], int kt) {
#pragma unroll
    for (int j = 0; j < 12; ++j) {
      const unsigned short* wp = Wt + (size_t)(j * 16 + ln15) * C_DIM + kt * 64 + g * 8;
      bf16x8 b0 = *(const bf16x8*)wp;
      bf16x8 b1 = *(const bf16x8*)(wp + 32);
      acc[j] = mfma16(af[0], b0, acc[j]);
      acc[j] = mfma16(af[1], b1, acc[j]);
    }
  };

  bf16x8 aA[2], aB[2];
  loadA(aA, 0);
  for (int kt = 0; kt < 16; kt += 2) {
    loadA(aB, kt + 1);
    compW(aA, kt);
    if (kt + 2 < 16) loadA(aA, kt + 2);
    compW(aB, kt + 1);
  }

  // epilogue: Q/K direct stores; V -> LDS transpose tile -> coalesced VTb
#pragma unroll
  for (int j = 0; j < 8; ++j) {
    const int mtx = j >> 2, nc = (j & 3) * 16;
    const float* bias = (mtx == 0) ? bq : bk;
    unsigned short* Out = (mtx == 0) ? Qb : Kb;
    float bvv = bias[nc + ln15] * ((mtx == 0) ? QSCALE : 1.0f);
#pragma unroll
    for (int i = 0; i < 4; ++i)
      Out[(m0 + wv * 16 + 4 * g + i) * 64 + nc + ln15] = f2bf(acc[j][i] + bvv);
  }
#pragma unroll
  for (int j = 8; j < 12; ++j) {
    const int nc = (j - 8) * 16;
    float bvv = bv[nc + ln15];
#pragma unroll
    for (int i = 0; i < 4; ++i)
      VTs[(nc + ln15) * 72 + wv * 16 + 4 * g + i] = f2bf(acc[j][i] + bvv);
  }
  __syncthreads();
  {
    int d = tid >> 2, t8 = (tid & 3) * 16;
    u32x4 v0 = *(const u32x4*)&VTs[d * 72 + t8];
    u32x4 v1 = *(const u32x4*)&VTs[d * 72 + t8 + 8];
    size_t b = m0 >> 11, tloc = m0 & 2047;
    *(u32x4*)&VTb[(b * 64 + d) * T_DIM + tloc + t8] = v0;
    *(u32x4*)&VTb[(b * 64 + d) * T_DIM + tloc + t8 + 8] = v1;
  }
}

// ---------------------------------------------------------------------------
// attn_flash: round-15 version EXACT (best measured: 53.0 total).
// ---------------------------------------------------------------------------
__global__ __launch_bounds__(256, 2) void attn_flash(
    const unsigned short* __restrict__ Qb,   // [B*T][64] (pre-scaled QSCALE)
    const unsigned short* __restrict__ Kb,   // [B*T][64]
    const unsigned short* __restrict__ VTb,  // [B][64][T]
    float* __restrict__ out)                 // [B*T][64] f32
{
  __shared__ __align__(16) short Ps[4][2 * 16 * 64];
  __shared__ __align__(16) float Zs[3][2][16 * 68];
  __shared__ float Ml[3][2][16][2];

  const int tid  = threadIdx.x;
  const int wv   = tid >> 6;
  const int lane = tid & 63;
  const int g    = lane >> 4;
  const int ln15 = lane & 15;

  const int qt = 63 - (blockIdx.x >> 3);
  const int b  = blockIdx.x & 7;
  const int r0 = qt * 32;
  const int ntiles = (qt >> 1) + 1;

  const size_t bT = (size_t)b * T_DIM;

  bf16x8 qa[2][2];
#pragma unroll
  for (int mt = 0; mt < 2; ++mt) {
    const unsigned short* qp = Qb + (bT + r0 + mt * 16 + ln15) * 64 + g * 8;
    qa[mt][0] = *(const bf16x8*)qp;
    qa[mt][1] = *(const bf16x8*)(qp + 32);
  }

  f32x4 acc[2][4];
#pragma unroll
  for (int mt = 0; mt < 2; ++mt)
#pragma unroll
    for (int dt = 0; dt < 4; ++dt) acc[mt][dt] = (f32x4){0.f, 0.f, 0.f, 0.f};
  float m_[2], l_[2];
#pragma unroll
  for (int mt = 0; mt < 2; ++mt) { m_[mt] = NEG_BIG; l_[mt] = 0.f; }

  char* myP = (char*)Ps[wv];

  for (int it = wv; it < ntiles; it += 4) {
    const int s0 = it * 64;
    bf16x8 kf[4][2];
#pragma unroll
    for (int nt = 0; nt < 4; ++nt) {
      const unsigned short* kp = Kb + (bT + s0 + nt * 16 + ln15) * 64 + g * 8;
      kf[nt][0] = *(const bf16x8*)kp;
      kf[nt][1] = *(const bf16x8*)(kp + 32);
    }
    bf16x8 vf[4][2];
#pragma unroll
    for (int dt = 0; dt < 4; ++dt) {
      const unsigned short* vp = VTb + ((size_t)b * 64 + dt * 16 + ln15) * T_DIM + s0 + g * 8;
      vf[dt][0] = *(const bf16x8*)vp;
      vf[dt][1] = *(const bf16x8*)(vp + 32);
    }
    f32x4 st[2][4];
    __builtin_amdgcn_s_setprio(1);
#pragma unroll
    for (int mt = 0; mt < 2; ++mt)
#pragma unroll
      for (int nt = 0; nt < 4; ++nt) {
        f32x4 a = (f32x4){0.f, 0.f, 0.f, 0.f};
        a = mfma16(kf[nt][0], qa[mt][0], a);
        a = mfma16(kf[nt][1], qa[mt][1], a);
        st[mt][nt] = a;
      }
    __builtin_amdgcn_s_setprio(0);
    if (s0 + 63 > r0) {
#pragma unroll
      for (int mt = 0; mt < 2; ++mt) {
        const int qg = r0 + mt * 16 + ln15;
#pragma unroll
        for (int nt = 0; nt < 4; ++nt) {
          const int kvb = s0 + nt * 16 + 4 * g;
#pragma unroll
          for (int i = 0; i < 4; ++i)
            if (kvb + i > qg) st[mt][nt][i] = NEG_BIG;
        }
      }
    }
#pragma unroll
    for (int mt = 0; mt < 2; ++mt) {
      f32x4 t4;
#pragma unroll
      for (int i = 0; i < 4; ++i)
        t4[i] = fmaxf(fmaxf(st[mt][0][i], st[mt][1][i]), fmaxf(st[mt][2][i], st[mt][3][i]));
      float mx = fmaxf(fmaxf(t4[0], t4[1]), fmaxf(t4[2], t4[3]));
      if (!__all((int)(mx <= m_[mt] + 8.0f))) {
        mx = fmaxf(mx, __shfl_xor(mx, 16));
        mx = fmaxf(mx, __shfl_xor(mx, 32));
        const float mn = fmaxf(m_[mt], mx);
        const float corr = exp2f(m_[mt] - mn);
        m_[mt] = mn;
        l_[mt] *= corr;
#pragma unroll
        for (int dt = 0; dt < 4; ++dt)
#pragma unroll
          for (int i = 0; i < 4; ++i)
            acc[mt][dt][i] *= corr;
      }
#pragma unroll
      for (int nt = 0; nt < 4; ++nt)
#pragma unroll
        for (int i = 0; i < 4; ++i)
          st[mt][nt][i] = exp2f(st[mt][nt][i] - m_[mt]);
      float ps = 0.f;
#pragma unroll
      for (int nt = 0; nt < 4; ++nt)
        ps += (st[mt][nt][0] + st[mt][nt][1]) + (st[mt][nt][2] + st[mt][nt][3]);
      l_[mt] += ps;
#pragma unroll
      for (int nt = 0; nt < 4; ++nt) {
        unsigned int lo_ = (unsigned int)f2bf(st[mt][nt][0]) | ((unsigned int)f2bf(st[mt][nt][1]) << 16);
        unsigned int hi_ = (unsigned int)f2bf(st[mt][nt][2]) | ((unsigned int)f2bf(st[mt][nt][3]) << 16);
        *(unsigned long long*)(myP + mt * 2048 + ln15 * 128 +
                               ((nt * 32 + g * 8) ^ ((ln15 & 7) << 4))) =
            ((unsigned long long)hi_ << 32) | lo_;
      }
    }
    bf16x8 pb[2][2];
#pragma unroll
    for (int mt = 0; mt < 2; ++mt)
#pragma unroll
      for (int kc = 0; kc < 2; ++kc)
        pb[mt][kc] = *(const bf16x8*)(myP + mt * 2048 + ln15 * 128 +
                                      ((kc * 64 + g * 16) ^ ((ln15 & 7) << 4)));
    __builtin_amdgcn_s_setprio(1);
#pragma unroll
    for (int mt = 0; mt < 2; ++mt)
#pragma unroll
      for (int dt = 0; dt < 4; ++dt) {
        acc[mt][dt] = mfma16(vf[dt][0], pb[mt][0], acc[mt][dt]);
        acc[mt][dt] = mfma16(vf[dt][1], pb[mt][1], acc[mt][dt]);
      }
    __builtin_amdgcn_s_setprio(0);
  }

#pragma unroll
  for (int mt = 0; mt < 2; ++mt) {
    l_[mt] += __shfl_xor(l_[mt], 16);
    l_[mt] += __shfl_xor(l_[mt], 32);
  }

  if (wv > 0) {
#pragma unroll
    for (int mt = 0; mt < 2; ++mt) {
#pragma unroll
      for (int dt = 0; dt < 4; ++dt)
        *(f32x4*)&Zs[wv - 1][mt][ln15 * 68 + dt * 16 + 4 * g] = acc[mt][dt];
      if (g == 0) {
        Ml[wv - 1][mt][ln15][0] = m_[mt];
        Ml[wv - 1][mt][ln15][1] = l_[mt];
      }
    }
  }
  __syncthreads();
  if (wv == 0) {
#pragma unroll
    for (int mt = 0; mt < 2; ++mt) {
      float mm = m_[mt];
#pragma unroll
      for (int w = 0; w < 3; ++w) mm = fmaxf(mm, Ml[w][mt][ln15][0]);
      const float e0 = exp2f(m_[mt] - mm);
      float lsum = l_[mt] * e0;
      float ew[3];
#pragma unroll
      for (int w = 0; w < 3; ++w) {
        ew[w] = exp2f(Ml[w][mt][ln15][0] - mm);
        lsum += Ml[w][mt][ln15][1] * ew[w];
      }
      const float inv = 1.0f / lsum;
      float* ob = out + (bT + r0 + mt * 16 + ln15) * 64;
#pragma unroll
      for (int dt = 0; dt < 4; ++dt) {
        f32x4 z;
#pragma unroll
        for (int i = 0; i < 4; ++i) {
          float zz = acc[mt][dt][i] * e0;
#pragma unroll
          for (int w = 0; w < 3; ++w)
            zz += Zs[w][mt][ln15 * 68 + dt * 16 + 4 * g + i] * ew[w];
          z[i] = zz * inv;
        }
        *(f32x4*)&ob[dt * 16 + 4 * g] = z;
      }
    }
  }
}

// ---------------------------------------------------------------------------
extern "C" void kernel_launch(void* const* d_in, const int* in_sizes, int n_in,
                              void* d_out, int out_size, void* d_ws, size_t ws_size,
                              hipStream_t stream)
{
  const float* x  = (const float*)d_in[0];
  const float* Wq = (const float*)d_in[1];
  const float* bq = (const float*)d_in[2];
  const float* Wk = (const float*)d_in[3];
  const float* bk = (const float*)d_in[4];
  const float* Wv = (const float*)d_in[5];
  const float* bv = (const float*)d_in[6];
  float* out = (float*)d_out;

  char* ws = (char*)d_ws;
  unsigned short* Wt  = (unsigned short*)(ws);                      // 384 KB
  unsigned short* Qb  = (unsigned short*)(ws + (1u << 19));         // 2 MB
  unsigned short* Kb  = (unsigned short*)(ws + (1u << 19) + (1u << 21));
  unsigned short* VTb = (unsigned short*)(ws + (1u << 19) + (2u << 21));

  prep_w<<<48, 256, 0, stream>>>(Wq, Wk, Wv, Wt);
  qkv_proj_mfma<<<256, 256, 0, stream>>>(x, Wt, bq, bk, bv, Qb, Kb, VTb);
  attn_flash<<<512, 256, 0, stream>>>(Qb, Kb, VTb, out);
}

// Round 20
// 53.057 us; speedup vs baseline: 2.4322x; 1.6966x over previous
//
#include <hip/hip_runtime.h>
#include <hip/hip_bf16.h>
#include <cstdint>
#include <cstddef>

typedef __attribute__((ext_vector_type(8))) short bf16x8;
typedef __attribute__((ext_vector_type(4))) float f32x4;
typedef __attribute__((ext_vector_type(4))) unsigned int u32x4;

#define T_DIM 2048
#define C_DIM 1024
#define B_DIM 8
#define NEG_BIG (-3.0e38f)
#define QSCALE 0.18033688011112042f   // (1/8) * log2(e): softmax in exp2 domain

__device__ __forceinline__ unsigned short f2bf(float f) {
  union { __hip_bfloat16 h; unsigned short u; } cv;
  cv.h = __float2bfloat16(f);
  return cv.u;
}
__device__ __forceinline__ f32x4 mfma16(bf16x8 a, bf16x8 b, f32x4 c) {
  return __builtin_amdgcn_mfma_f32_16x16x32_bf16(a, b, c, 0, 0, 0);
}

// ---------------------------------------------------------------------------
// prep_w: W [1024][64] f32 -> Wt [3][64][1024] bf16 (transposed; Wq scaled by
// (1/8)*log2e so softmax runs in exp2 domain).
// ---------------------------------------------------------------------------
__global__ __launch_bounds__(256) void prep_w(
    const float* __restrict__ Wq, const float* __restrict__ Wk,
    const float* __restrict__ Wv, unsigned short* __restrict__ Wt)
{
  const int mtx = blockIdx.x >> 4;
  const int k0  = (blockIdx.x & 15) * 64;
  const float* W = (mtx == 0) ? Wq : ((mtx == 1) ? Wk : Wv);
  const float scale = (mtx == 0) ? QSCALE : 1.0f;
  __shared__ float Ws[64][65];
  const int t = threadIdx.x;
#pragma unroll
  for (int j = 0; j < 4; ++j) {
    int r = (t >> 4) + 16 * j;
    int c = (t & 15) * 4;
    union { float4 f4; float f[4]; } uv;
    uv.f4 = *(const float4*)&W[(size_t)(k0 + r) * 64 + c];
#pragma unroll
    for (int jj = 0; jj < 4; ++jj) Ws[c + jj][r] = uv.f[jj] * scale;
  }
  __syncthreads();
#pragma unroll
  for (int q = 0; q < 2; ++q) {
    int g_ = t + 256 * q;
    int d  = g_ >> 3;
    int ko = (g_ & 7) * 8;
    union { unsigned short u[8]; u32x4 v; } pk;
#pragma unroll
    for (int jj = 0; jj < 8; ++jj) pk.u[jj] = f2bf(Ws[d][ko + jj]);
    *(u32x4*)&Wt[((size_t)mtx * 64 + d) * C_DIM + k0 + ko] = pk.v;
  }
}

// ---------------------------------------------------------------------------
// qkv_proj_mfma: round-12 pipelined version (512 x 32 rows) — best measured.
// Coalesced cooperative staging (the LDS round-trip BUYS coalescing; r19's
// direct-gather variant was 3x slower). Loads in flight across barriers.
// ---------------------------------------------------------------------------
__global__ __launch_bounds__(256) void qkv_proj_mfma(
    const float* __restrict__ x,
    const unsigned short* __restrict__ Wt,
    const float* __restrict__ bq, const float* __restrict__ bk, const float* __restrict__ bv,
    unsigned short* __restrict__ Qb, unsigned short* __restrict__ Kb,
    unsigned short* __restrict__ VTb)
{
  __shared__ __align__(16) short Xs[2][32 * 64];
  __shared__ __align__(16) short Wsb[2][3 * 64 * 64];
  __shared__ __align__(16) unsigned short VTs[64 * 40];

  const int tid = threadIdx.x;
  const int wv = tid >> 6, lane = tid & 63, g = lane >> 4, ln15 = lane & 15;
  const size_t m0 = (size_t)blockIdx.x * 32;

  f32x4 acc[2][3];
#pragma unroll
  for (int mt = 0; mt < 2; ++mt)
#pragma unroll
    for (int j = 0; j < 3; ++j) acc[mt][j] = (f32x4){0.f, 0.f, 0.f, 0.f};

  float4 xA[2], xB[2];
  u32x4 wr[6];

  auto issueX = [&](float4 (&xr)[2], int kt) {
    if (kt >= 16) return;
#pragma unroll
    for (int q = 0; q < 2; ++q) {
      int g_ = tid + 256 * q;
      int r = g_ >> 4, c4 = (g_ & 15) * 4;
      xr[q] = *(const float4*)&x[(m0 + r) * C_DIM + kt * 64 + c4];
    }
  };
  auto issueW = [&](int kt) {
    if (kt >= 16) return;
#pragma unroll
    for (int mt = 0; mt < 3; ++mt)
#pragma unroll
      for (int q = 0; q < 2; ++q) {
        int g_ = tid + 256 * q;
        int d = g_ >> 3, ko = (g_ & 7) * 8;
        wr[mt * 2 + q] = *(const u32x4*)&Wt[((size_t)mt * 64 + d) * C_DIM + kt * 64 + ko];
      }
  };
  auto writeXb = [&](int nb, const float4 (&xr)[2]) {
#pragma unroll
    for (int q = 0; q < 2; ++q) {
      int g_ = tid + 256 * q;
      int r = g_ >> 4, c4 = (g_ & 15) * 4;
      const float* f = (const float*)&xr[q];
      union { unsigned short u[4]; unsigned long long ll; } pk;
#pragma unroll
      for (int jj = 0; jj < 4; ++jj) pk.u[jj] = f2bf(f[jj]);
      *(unsigned long long*)((char*)Xs[nb] + r * 128 + ((c4 * 2) ^ ((r & 7) << 4))) = pk.ll;
    }
  };
  auto writeWb = [&](int nb) {
#pragma unroll
    for (int mt = 0; mt < 3; ++mt)
#pragma unroll
      for (int q = 0; q < 2; ++q) {
        int g_ = tid + 256 * q;
        int d = g_ >> 3, ko = (g_ & 7) * 8;
        *(u32x4*)((char*)Wsb[nb] + mt * 8192 + d * 128 + ((ko * 2) ^ ((d & 7) << 4))) = wr[mt * 2 + q];
      }
  };
  auto compute = [&](int nb) {
#pragma unroll
    for (int kc = 0; kc < 2; ++kc) {
      bf16x8 a[2];
#pragma unroll
      for (int mt = 0; mt < 2; ++mt) {
        int xr = mt * 16 + ln15;
        a[mt] = *(const bf16x8*)((const char*)Xs[nb] + xr * 128 + ((kc * 64 + g * 16) ^ ((xr & 7) << 4)));
      }
#pragma unroll
      for (int j = 0; j < 3; ++j) {
        int ntg = wv * 3 + j;
        int mtx = ntg >> 2, nc = (ntg & 3) * 16;
        int wrow = nc + ln15;
        bf16x8 bb = *(const bf16x8*)((const char*)Wsb[nb] + mtx * 8192 + wrow * 128 + ((kc * 64 + g * 16) ^ ((wrow & 7) << 4)));
#pragma unroll
        for (int mt = 0; mt < 2; ++mt)
          acc[mt][j] = mfma16(a[mt], bb, acc[mt][j]);
      }
    }
  };

  issueX(xA, 0); issueW(0);
  writeXb(0, xA); writeWb(0);
  issueX(xB, 1);
  __syncthreads();

  for (int kt = 0; kt < 16; kt += 2) {
    issueW(kt + 1);
    issueX(xA, kt + 2);
    compute(0);
    if (kt + 1 < 16) { writeXb(1, xB); writeWb(1); }
    __syncthreads();
    if (kt + 1 < 16) {
      issueW(kt + 2);
      issueX(xB, kt + 3);
      compute(1);
      if (kt + 2 < 16) { writeXb(0, xA); writeWb(0); }
      __syncthreads();
    }
  }

#pragma unroll
  for (int j = 0; j < 3; ++j) {
    int ntg = wv * 3 + j;
    int mtx = ntg >> 2, nc = (ntg & 3) * 16;
    if (mtx < 2) {
      const float* bias = (mtx == 0) ? bq : bk;
      unsigned short* Out = (mtx == 0) ? Qb : Kb;
      float bvv = bias[nc + ln15] * ((mtx == 0) ? QSCALE : 1.0f);
#pragma unroll
      for (int mt = 0; mt < 2; ++mt)
#pragma unroll
        for (int i = 0; i < 4; ++i)
          Out[(m0 + mt * 16 + 4 * g + i) * 64 + nc + ln15] = f2bf(acc[mt][j][i] + bvv);
    } else {
      float bvv = bv[nc + ln15];
#pragma unroll
      for (int mt = 0; mt < 2; ++mt)
#pragma unroll
        for (int i = 0; i < 4; ++i)
          VTs[(nc + ln15) * 40 + mt * 16 + 4 * g + i] = f2bf(acc[mt][j][i] + bvv);
    }
  }
  __syncthreads();
  {
    int d = tid >> 2, t8 = (tid & 3) * 8;
    u32x4 v0 = *(const u32x4*)&VTs[d * 40 + t8];
    size_t b = m0 >> 11, tloc = m0 & 2047;
    *(u32x4*)&VTb[(b * 64 + d) * T_DIM + tloc + t8] = v0;
  }
}

// ---------------------------------------------------------------------------
// attn_flash: round-15 version EXACT (best measured). Swapped-operand QK^T
// (per-lane scalar softmax state), defer-max THR=8 (exp2 domain), deferred
// cross-lane l-reduce, s_setprio around MFMA clusters, in-kernel 4-way merge.
// ---------------------------------------------------------------------------
__global__ __launch_bounds__(256, 2) void attn_flash(
    const unsigned short* __restrict__ Qb,   // [B*T][64] (pre-scaled QSCALE)
    const unsigned short* __restrict__ Kb,   // [B*T][64]
    const unsigned short* __restrict__ VTb,  // [B][64][T]
    float* __restrict__ out)                 // [B*T][64] f32
{
  __shared__ __align__(16) short Ps[4][2 * 16 * 64];
  __shared__ __align__(16) float Zs[3][2][16 * 68];
  __shared__ float Ml[3][2][16][2];

  const int tid  = threadIdx.x;
  const int wv   = tid >> 6;
  const int lane = tid & 63;
  const int g    = lane >> 4;
  const int ln15 = lane & 15;

  const int qt = 63 - (blockIdx.x >> 3);
  const int b  = blockIdx.x & 7;
  const int r0 = qt * 32;
  const int ntiles = (qt >> 1) + 1;

  const size_t bT = (size_t)b * T_DIM;

  bf16x8 qa[2][2];
#pragma unroll
  for (int mt = 0; mt < 2; ++mt) {
    const unsigned short* qp = Qb + (bT + r0 + mt * 16 + ln15) * 64 + g * 8;
    qa[mt][0] = *(const bf16x8*)qp;
    qa[mt][1] = *(const bf16x8*)(qp + 32);
  }

  f32x4 acc[2][4];
#pragma unroll
  for (int mt = 0; mt < 2; ++mt)
#pragma unroll
    for (int dt = 0; dt < 4; ++dt) acc[mt][dt] = (f32x4){0.f, 0.f, 0.f, 0.f};
  float m_[2], l_[2];
#pragma unroll
  for (int mt = 0; mt < 2; ++mt) { m_[mt] = NEG_BIG; l_[mt] = 0.f; }

  char* myP = (char*)Ps[wv];

  for (int it = wv; it < ntiles; it += 4) {
    const int s0 = it * 64;
    bf16x8 kf[4][2];
#pragma unroll
    for (int nt = 0; nt < 4; ++nt) {
      const unsigned short* kp = Kb + (bT + s0 + nt * 16 + ln15) * 64 + g * 8;
      kf[nt][0] = *(const bf16x8*)kp;
      kf[nt][1] = *(const bf16x8*)(kp + 32);
    }
    bf16x8 vf[4][2];
#pragma unroll
    for (int dt = 0; dt < 4; ++dt) {
      const unsigned short* vp = VTb + ((size_t)b * 64 + dt * 16 + ln15) * T_DIM + s0 + g * 8;
      vf[dt][0] = *(const bf16x8*)vp;
      vf[dt][1] = *(const bf16x8*)(vp + 32);
    }
    f32x4 st[2][4];
    __builtin_amdgcn_s_setprio(1);
#pragma unroll
    for (int mt = 0; mt < 2; ++mt)
#pragma unroll
      for (int nt = 0; nt < 4; ++nt) {
        f32x4 a = (f32x4){0.f, 0.f, 0.f, 0.f};
        a = mfma16(kf[nt][0], qa[mt][0], a);
        a = mfma16(kf[nt][1], qa[mt][1], a);
        st[mt][nt] = a;
      }
    __builtin_amdgcn_s_setprio(0);
    if (s0 + 63 > r0) {
#pragma unroll
      for (int mt = 0; mt < 2; ++mt) {
        const int qg = r0 + mt * 16 + ln15;
#pragma unroll
        for (int nt = 0; nt < 4; ++nt) {
          const int kvb = s0 + nt * 16 + 4 * g;
#pragma unroll
          for (int i = 0; i < 4; ++i)
            if (kvb + i > qg) st[mt][nt][i] = NEG_BIG;
        }
      }
    }
#pragma unroll
    for (int mt = 0; mt < 2; ++mt) {
      f32x4 t4;
#pragma unroll
      for (int i = 0; i < 4; ++i)
        t4[i] = fmaxf(fmaxf(st[mt][0][i], st[mt][1][i]), fmaxf(st[mt][2][i], st[mt][3][i]));
      float mx = fmaxf(fmaxf(t4[0], t4[1]), fmaxf(t4[2], t4[3]));
      if (!__all((int)(mx <= m_[mt] + 8.0f))) {
        mx = fmaxf(mx, __shfl_xor(mx, 16));
        mx = fmaxf(mx, __shfl_xor(mx, 32));
        const float mn = fmaxf(m_[mt], mx);
        const float corr = exp2f(m_[mt] - mn);
        m_[mt] = mn;
        l_[mt] *= corr;
#pragma unroll
        for (int dt = 0; dt < 4; ++dt)
#pragma unroll
          for (int i = 0; i < 4; ++i)
            acc[mt][dt][i] *= corr;
      }
#pragma unroll
      for (int nt = 0; nt < 4; ++nt)
#pragma unroll
        for (int i = 0; i < 4; ++i)
          st[mt][nt][i] = exp2f(st[mt][nt][i] - m_[mt]);
      float ps = 0.f;
#pragma unroll
      for (int nt = 0; nt < 4; ++nt)
        ps += (st[mt][nt][0] + st[mt][nt][1]) + (st[mt][nt][2] + st[mt][nt][3]);
      l_[mt] += ps;
#pragma unroll
      for (int nt = 0; nt < 4; ++nt) {
        unsigned int lo_ = (unsigned int)f2bf(st[mt][nt][0]) | ((unsigned int)f2bf(st[mt][nt][1]) << 16);
        unsigned int hi_ = (unsigned int)f2bf(st[mt][nt][2]) | ((unsigned int)f2bf(st[mt][nt][3]) << 16);
        *(unsigned long long*)(myP + mt * 2048 + ln15 * 128 +
                               ((nt * 32 + g * 8) ^ ((ln15 & 7) << 4))) =
            ((unsigned long long)hi_ << 32) | lo_;
      }
    }
    bf16x8 pb[2][2];
#pragma unroll
    for (int mt = 0; mt < 2; ++mt)
#pragma unroll
      for (int kc = 0; kc < 2; ++kc)
        pb[mt][kc] = *(const bf16x8*)(myP + mt * 2048 + ln15 * 128 +
                                      ((kc * 64 + g * 16) ^ ((ln15 & 7) << 4)));
    __builtin_amdgcn_s_setprio(1);
#pragma unroll
    for (int mt = 0; mt < 2; ++mt)
#pragma unroll
      for (int dt = 0; dt < 4; ++dt) {
        acc[mt][dt] = mfma16(vf[dt][0], pb[mt][0], acc[mt][dt]);
        acc[mt][dt] = mfma16(vf[dt][1], pb[mt][1], acc[mt][dt]);
      }
    __builtin_amdgcn_s_setprio(0);
  }

#pragma unroll
  for (int mt = 0; mt < 2; ++mt) {
    l_[mt] += __shfl_xor(l_[mt], 16);
    l_[mt] += __shfl_xor(l_[mt], 32);
  }

  if (wv > 0) {
#pragma unroll
    for (int mt = 0; mt < 2; ++mt) {
#pragma unroll
      for (int dt = 0; dt < 4; ++dt)
        *(f32x4*)&Zs[wv - 1][mt][ln15 * 68 + dt * 16 + 4 * g] = acc[mt][dt];
      if (g == 0) {
        Ml[wv - 1][mt][ln15][0] = m_[mt];
        Ml[wv - 1][mt][ln15][1] = l_[mt];
      }
    }
  }
  __syncthreads();
  if (wv == 0) {
#pragma unroll
    for (int mt = 0; mt < 2; ++mt) {
      float mm = m_[mt];
#pragma unroll
      for (int w = 0; w < 3; ++w) mm = fmaxf(mm, Ml[w][mt][ln15][0]);
      const float e0 = exp2f(m_[mt] - mm);
      float lsum = l_[mt] * e0;
      float ew[3];
#pragma unroll
      for (int w = 0; w < 3; ++w) {
        ew[w] = exp2f(Ml[w][mt][ln15][0] - mm);
        lsum += Ml[w][mt][ln15][1] * ew[w];
      }
      const float inv = 1.0f / lsum;
      float* ob = out + (bT + r0 + mt * 16 + ln15) * 64;
#pragma unroll
      for (int dt = 0; dt < 4; ++dt) {
        f32x4 z;
#pragma unroll
        for (int i = 0; i < 4; ++i) {
          float zz = acc[mt][dt][i] * e0;
#pragma unroll
          for (int w = 0; w < 3; ++w)
            zz += Zs[w][mt][ln15 * 68 + dt * 16 + 4 * g + i] * ew[w];
          z[i] = zz * inv;
        }
        *(f32x4*)&ob[dt * 16 + 4 * g] = z;
      }
    }
  }
}

// ---------------------------------------------------------------------------
extern "C" void kernel_launch(void* const* d_in, const int* in_sizes, int n_in,
                              void* d_out, int out_size, void* d_ws, size_t ws_size,
                              hipStream_t stream)
{
  const float* x  = (const float*)d_in[0];
  const float* Wq = (const float*)d_in[1];
  const float* bq = (const float*)d_in[2];
  const float* Wk = (const float*)d_in[3];
  const float* bk = (const float*)d_in[4];
  const float* Wv = (const float*)d_in[5];
  const float* bv = (const float*)d_in[6];
  float* out = (float*)d_out;

  char* ws = (char*)d_ws;
  unsigned short* Wt  = (unsigned short*)(ws);                      // 384 KB
  unsigned short* Qb  = (unsigned short*)(ws + (1u << 19));         // 2 MB
  unsigned short* Kb  = (unsigned short*)(ws + (1u << 19) + (1u << 21));
  unsigned short* VTb = (unsigned short*)(ws + (1u << 19) + (2u << 21));

  prep_w<<<48, 256, 0, stream>>>(Wq, Wk, Wv, Wt);
  qkv_proj_mfma<<<512, 256, 0, stream>>>(x, Wt, bq, bk, bv, Qb, Kb, VTb);
  attn_flash<<<512, 256, 0, stream>>>(Qb, Kb, VTb, out);
}